// Round 8
// baseline (639.800 us; speedup 1.0000x reference)
//
#include <hip/hip_runtime.h>
#include <hip/hip_bf16.h>
#include <math.h>

#define F_IN 200
#define HDIM 64
#define NPG  400
#define EPG  6400
#define KSEL 200   // NPG/2

typedef __attribute__((ext_vector_type(4))) float f32x4;
typedef __attribute__((ext_vector_type(8))) short s16x8;

// RNE float -> bf16 bits
__device__ __forceinline__ unsigned int bf16_rne(float x) {
    unsigned int b = __float_as_uint(x);
    return (b + 0x7FFFu + ((b >> 16) & 1u)) >> 16;
}

// split x into bf16 hi + bf16 lo (x ~= hi + lo, rel err ~2^-17)
__device__ __forceinline__ void split8(f32x4 v0, f32x4 v1, s16x8& h, s16x8& l) {
    float x[8] = {v0.x, v0.y, v0.z, v0.w, v1.x, v1.y, v1.z, v1.w};
#pragma unroll
    for (int j = 0; j < 8; j++) {
        unsigned int hb = bf16_rne(x[j]);
        float hf = __uint_as_float(hb << 16);
        float r = x[j] - hf;
        unsigned int lb = bf16_rne(r);
        h[j] = (short)hb;
        l[j] = (short)lb;
    }
}

// ---------------- pack W ([K,64]|[K,64] fp32) -> fragment-ordered bf16 pairs --
// WF layout: frag f = (kc*8+nf)*2+p (p=0 hi, p=1 lo); short index f*512+lane*8+j
// fragment element: k = kc*32 + (lane>>4)*8 + j ; n = nf*16 + (lane&15)
__global__ void pack_wf(const float* __restrict__ Wl, const float* __restrict__ Wr,
                        short* __restrict__ WF, int K, int KC) {
    int idx = blockIdx.x * blockDim.x + threadIdx.x;
    if (idx >= KC * 4096) return;
    int j    = idx & 7;
    int lane = (idx >> 3) & 63;
    int nf   = (idx >> 9) & 7;
    int kc   = idx >> 12;
    int k = kc * 32 + (lane >> 4) * 8 + j;
    int n = nf * 16 + (lane & 15);
    float v = 0.f;
    if (k < K) v = (n < 64) ? Wl[k * 64 + n] : Wr[k * 64 + (n - 64)];
    unsigned int hb = bf16_rne(v);
    float hf = __uint_as_float(hb << 16);
    unsigned int lb = bf16_rne(v - hf);
    WF[(size_t)((kc * 8 + nf) * 2 + 0) * 512 + lane * 8 + j] = (short)hb;
    WF[(size_t)((kc * 8 + nf) * 2 + 1) * 512 + lane * 8 + j] = (short)lb;
}

// ---------------- CSR build: one block per graph ----------------
__global__ __launch_bounds__(256) void csr_build(
    const int* __restrict__ esrc, const int* __restrict__ edst,
    int* __restrict__ csr_src, int* __restrict__ rowptr,
    int* __restrict__ degs, float* __restrict__ invdeg)
{
    __shared__ int cnt[NPG];
    __shared__ int off[NPG];
    __shared__ int cur[NPG];
    const int g = blockIdx.x, tid = threadIdx.x;
    const int ebase = g * EPG, nodebase = g * NPG;
    for (int i = tid; i < NPG; i += 256) cnt[i] = 0;
    __syncthreads();
    for (int e = tid; e < EPG; e += 256)
        atomicAdd(&cnt[edst[ebase + e] - nodebase], 1);
    __syncthreads();
    if (tid == 0) {
        int run = 0;
        for (int i = 0; i < NPG; i++) { off[i] = run; run += cnt[i]; }
    }
    __syncthreads();
    for (int i = tid; i < NPG; i += 256) {
        cur[i] = off[i];
        rowptr[nodebase + i] = off[i];
        degs[nodebase + i] = cnt[i];
        invdeg[nodebase + i] = 1.f / fmaxf((float)cnt[i], 1.f);
    }
    __syncthreads();
    for (int e = tid; e < EPG; e += 256) {
        int ld = edst[ebase + e] - nodebase;
        int p = atomicAdd(&cur[ld], 1);
        csr_src[ebase + p] = esrc[ebase + e] - nodebase;  // local src
    }
}

// ---------------- fused per-graph layer: GEMM + aggregate + combine ----------
// Block = 1 graph, 1024 threads = 16 waves.
// Phase A: yz = h @ [Wl|Wr] via split-bf16 MFMA; y (cols 0-63) -> LDS,
//          z (cols 64-127) -> zbuf (global, L2-hot).
// Phase B: per-node CSR aggregation from LDS y; out = relu(agg*inv+b+z)+resid.
// Phase C/D (DOSCORE): GraphConv score, stable top-k, tanh-weighted mean pool,
//          classifier + log_softmax.
template <int K, int LDX, int KC, int DOSCORE>
__global__ __launch_bounds__(1024) void layer_fused(
    const float* __restrict__ X,
    const short* __restrict__ WF,
    const int* __restrict__ csr_src, const int* __restrict__ rowptr,
    const int* __restrict__ degs, const float* __restrict__ invdeg,
    const float* __restrict__ bias,
    const float* __restrict__ resid,     // nullptr for layer1
    float* __restrict__ zbuf,            // [N,64] scratch
    float* __restrict__ P,               // [N,64] output
    const float* __restrict__ Wpr, const float* __restrict__ bpr,
    const float* __restrict__ Wpo,
    const float* __restrict__ Wlin, const float* __restrict__ blin,
    float* __restrict__ out)
{
    __shared__ float y[NPG * 64];        // 102400 B
    __shared__ int   csr_l[EPG];         // 25600 B
    __shared__ float t0s[NPG], ss[NPG], wsel[NPG];
    __shared__ float pp[16 * 64];
    __shared__ float pooled[64];
    __shared__ float lgs[2];

    const int g = blockIdx.x, tid = threadIdx.x;
    const int wave = tid >> 6, lane = tid & 63;
    const int nodebase = g * NPG, ebase = g * EPG;
    const s16x8* WFv = (const s16x8*)WF;

    // stage CSR slice
    for (int e = tid; e < EPG; e += 1024) csr_l[e] = csr_src[ebase + e];

    // ---- Phase A: per-wave m-fragments (25 frags of 16 rows; 25*16=400) ----
    const int arow = lane & 15;
    const int ak0  = (lane >> 4) * 8;
    const f32x4 zero4 = (f32x4){0.f, 0.f, 0.f, 0.f};
    for (int f = wave; f < 25; f += 16) {
        const size_t xrow = (size_t)(nodebase + f * 16 + arow) * LDX;
        f32x4 acc[8];
#pragma unroll
        for (int nf = 0; nf < 8; nf++) acc[nf] = zero4;

        f32x4 pa0, pa1;
#define LOADA(kc_) {                                                   \
            int k0 = (kc_) * 32 + ak0;                                 \
            pa0 = (k0 + 4 <= K) ? *(const f32x4*)&X[xrow + k0] : zero4;\
            pa1 = (k0 + 8 <= K) ? *(const f32x4*)&X[xrow + k0 + 4] : zero4; }

        LOADA(0);
        for (int kc = 0; kc < KC; kc++) {
            s16x8 ah, al;
            split8(pa0, pa1, ah, al);
            if (kc + 1 < KC) LOADA(kc + 1);          // prefetch next A chunk
            const s16x8* wb = WFv + (size_t)(kc * 8) * 128 + lane;
            s16x8 wh = wb[0], wl = wb[64];
#pragma unroll
            for (int nf = 0; nf < 8; nf++) {
                s16x8 wh2, wl2;
                if (nf < 7) { wh2 = wb[(nf + 1) * 128]; wl2 = wb[(nf + 1) * 128 + 64]; }
                acc[nf] = __builtin_amdgcn_mfma_f32_16x16x32_bf16(ah, wh, acc[nf], 0, 0, 0);
                acc[nf] = __builtin_amdgcn_mfma_f32_16x16x32_bf16(al, wh, acc[nf], 0, 0, 0);
                acc[nf] = __builtin_amdgcn_mfma_f32_16x16x32_bf16(ah, wl, acc[nf], 0, 0, 0);
                wh = wh2; wl = wl2;
            }
        }
#undef LOADA
        // store: D reg r -> row (lane>>4)*4+r, col nf*16+(lane&15)
        const int drow = f * 16 + (lane >> 4) * 4;
        const int dcol = lane & 15;
#pragma unroll
        for (int nf = 0; nf < 4; nf++)
#pragma unroll
            for (int r = 0; r < 4; r++)
                y[(drow + r) * 64 + nf * 16 + dcol] = acc[nf][r];
#pragma unroll
        for (int nf = 4; nf < 8; nf++)
#pragma unroll
            for (int r = 0; r < 4; r++)
                zbuf[(size_t)(nodebase + drow + r) * 64 + (nf - 4) * 16 + dcol] = acc[nf][r];
    }
    __syncthreads();

    // ---- Phase B: aggregate + combine (wave per node, lane = feature) ----
    const float blane = bias[lane];
    for (int t = 0; t < 25; t++) {
        const int node = t * 16 + wave;
        const int start = rowptr[nodebase + node];
        const int dg = degs[nodebase + node];
        float acc = 0.f;
        int j = 0;
        for (; j + 4 <= dg; j += 4) {
            int s0 = csr_l[start + j];
            int s1 = csr_l[start + j + 1];
            int s2 = csr_l[start + j + 2];
            int s3 = csr_l[start + j + 3];
            acc += y[s0 * 64 + lane] + y[s1 * 64 + lane]
                 + y[s2 * 64 + lane] + y[s3 * 64 + lane];
        }
        for (; j < dg; j++) acc += y[csr_l[start + j] * 64 + lane];

        float v = acc * invdeg[nodebase + node] + blane
                + zbuf[(size_t)(nodebase + node) * 64 + lane];
        v = fmaxf(v, 0.f);
        if (resid) v += resid[(size_t)(nodebase + node) * 64 + lane];
        P[(size_t)(nodebase + node) * 64 + lane] = v;

        if constexpr (DOSCORE) {
            float a = v * Wpr[lane];
            float b = v * Wpo[lane];
#pragma unroll
            for (int o = 32; o; o >>= 1) {
                a += __shfl_xor(a, o);
                b += __shfl_xor(b, o);
            }
            if (lane == 0) { t0s[node] = a; ss[node] = bpr[0] + b; }
        }
    }

    if constexpr (DOSCORE) {
        __syncthreads();
        // score edge aggregation (add, via CSR): s[i] += sum t0[src]
        for (int node = wave; node < NPG; node += 16) {
            const int start = rowptr[nodebase + node];
            const int dg = degs[nodebase + node];
            float a = 0.f;
            for (int j = lane; j < dg; j += 64) a += t0s[csr_l[start + j]];
#pragma unroll
            for (int o = 32; o; o >>= 1) a += __shfl_xor(a, o);
            if (lane == 0) ss[node] += a;
        }
        __syncthreads();
        // stable top-k by counting (matches lax.top_k tie-breaking)
        if (tid < NPG) {
            float si = ss[tid];
            int cnt = 0;
            for (int j = 0; j < NPG; j++) {
                float sj = ss[j];
                cnt += (sj > si) || (sj == si && j < tid);
            }
            wsel[tid] = (cnt < KSEL) ? tanhf(si) * (1.f / KSEL) : 0.f;
        }
        __syncthreads();
        // pooled mean (tanh-weighted), x3 re-read from P (L2-hot, own rows)
        float a = 0.f;
        for (int t = 0; t < 25; t++) {
            const int node = t * 16 + wave;
            float wv = wsel[node];
            a += wv * P[(size_t)(nodebase + node) * 64 + lane];
        }
        pp[wave * 64 + lane] = a;
        __syncthreads();
        if (tid < 64) {
            float s = 0.f;
#pragma unroll
            for (int i = 0; i < 16; i++) s += pp[i * 64 + tid];
            pooled[tid] = s;
        }
        __syncthreads();
        if (tid < 2) {
            float l = blin[tid];
            for (int d = 0; d < 64; d++) l += pooled[d] * Wlin[d * 2 + tid];
            lgs[tid] = l;
        }
        __syncthreads();
        if (tid < 2) {
            float m = fmaxf(lgs[0], lgs[1]);
            float lse = m + logf(expf(lgs[0] - m) + expf(lgs[1] - m));
            out[g * 2 + tid] = lgs[tid] - lse;
        }
    }
}

extern "C" void kernel_launch(void* const* d_in, const int* in_sizes, int n_in,
                              void* d_out, int out_size, void* d_ws, size_t ws_size,
                              hipStream_t stream) {
    const float* x    = (const float*)d_in[0];
    const int*   eidx = (const int*)d_in[1];
    const float* W1l  = (const float*)d_in[3];
    const float* W1r  = (const float*)d_in[4];
    const float* b1   = (const float*)d_in[5];
    const float* W2l  = (const float*)d_in[6];
    const float* W2r  = (const float*)d_in[7];
    const float* b2   = (const float*)d_in[8];
    const float* W3l  = (const float*)d_in[9];
    const float* W3r  = (const float*)d_in[10];
    const float* b3   = (const float*)d_in[11];
    const float* Wpr  = (const float*)d_in[12];
    const float* bpr  = (const float*)d_in[13];
    const float* Wpo  = (const float*)d_in[14];
    const float* Wlin = (const float*)d_in[15];
    const float* blin = (const float*)d_in[16];

    const int N = in_sizes[0] / F_IN;       // 204800
    const int E = in_sizes[1] / 2;          // 3276800
    const int B = N / NPG;                  // 512
    const int* esrc = eidx;
    const int* edst = eidx + E;

    float* ws = (float*)d_ws;
    float* zbuf   = ws;                                  // [N,64]
    float* P0     = zbuf + (size_t)N * 64;               // [N,64]
    float* P1     = P0 + (size_t)N * 64;                 // [N,64]
    float* invdeg = P1 + (size_t)N * 64;                 // [N]
    short* WF1    = (short*)(invdeg + N);                // 7*8*2*512 shorts
    short* WF2    = WF1 + 57344;                         // 2*8*2*512 shorts
    short* WF3    = WF2 + 16384;
    int*   csr    = (int*)(WF3 + 16384);                 // [E] local src by dst
    int*   rowptr = csr + E;                             // [N] local offsets
    int*   degs   = rowptr + N;                          // [N]

    pack_wf<<<(7 * 4096 + 255) / 256, 256, 0, stream>>>(W1l, W1r, WF1, 200, 7);
    pack_wf<<<(2 * 4096 + 255) / 256, 256, 0, stream>>>(W2l, W2r, WF2, 64, 2);
    pack_wf<<<(2 * 4096 + 255) / 256, 256, 0, stream>>>(W3l, W3r, WF3, 64, 2);

    csr_build<<<B, 256, 0, stream>>>(esrc, edst, csr, rowptr, degs, invdeg);

    // layer 1: x1 -> P0
    layer_fused<200, 200, 7, 0><<<B, 1024, 0, stream>>>(
        x, WF1, csr, rowptr, degs, invdeg, b1, nullptr, zbuf, P0,
        Wpr, bpr, Wpo, Wlin, blin, (float*)d_out);
    // layer 2: x2 = relu(sage(x1))+x1 -> P1
    layer_fused<64, 64, 2, 0><<<B, 1024, 0, stream>>>(
        P0, WF2, csr, rowptr, degs, invdeg, b2, P0, zbuf, P1,
        Wpr, bpr, Wpo, Wlin, blin, (float*)d_out);
    // layer 3 + score/pool/classifier: x3 -> P0, logits -> d_out
    layer_fused<64, 64, 2, 1><<<B, 1024, 0, stream>>>(
        P1, WF3, csr, rowptr, degs, invdeg, b3, P1, zbuf, P0,
        Wpr, bpr, Wpo, Wlin, blin, (float*)d_out);
}

// Round 9
// 493.948 us; speedup vs baseline: 1.2953x; 1.2953x over previous
//
#include <hip/hip_runtime.h>
#include <hip/hip_bf16.h>
#include <math.h>

#define F_IN 200
#define HDIM 64
#define NPG  400
#define EPG  6400
#define KSEL 200   // NPG/2

typedef __attribute__((ext_vector_type(4))) float f32x4;
typedef __attribute__((ext_vector_type(8))) short s16x8;

// RNE float -> bf16 bits
__device__ __forceinline__ unsigned int bf16_rne(float x) {
    unsigned int b = __float_as_uint(x);
    return (b + 0x7FFFu + ((b >> 16) & 1u)) >> 16;
}

// split x into bf16 hi + bf16 lo (x ~= hi + lo, rel err ~2^-17)
__device__ __forceinline__ void split8(f32x4 v0, f32x4 v1, s16x8& h, s16x8& l) {
    float x[8] = {v0.x, v0.y, v0.z, v0.w, v1.x, v1.y, v1.z, v1.w};
#pragma unroll
    for (int j = 0; j < 8; j++) {
        unsigned int hb = bf16_rne(x[j]);
        float hf = __uint_as_float(hb << 16);
        float r = x[j] - hf;
        unsigned int lb = bf16_rne(r);
        h[j] = (short)hb;
        l[j] = (short)lb;
    }
}

// ---------------- pack W ([K,64]|[K,64] fp32) -> fragment-ordered bf16 pairs --
// WF layout: frag f = (kc*8+nf)*2+p (p=0 hi, p=1 lo); short index f*512+lane*8+j
// fragment element: k = kc*32 + (lane>>4)*8 + j ; n = nf*16 + (lane&15)
__global__ void pack_wf(const float* __restrict__ Wl, const float* __restrict__ Wr,
                        short* __restrict__ WF, int K, int KC) {
    int idx = blockIdx.x * blockDim.x + threadIdx.x;
    if (idx >= KC * 4096) return;
    int j    = idx & 7;
    int lane = (idx >> 3) & 63;
    int nf   = (idx >> 9) & 7;
    int kc   = idx >> 12;
    int k = kc * 32 + (lane >> 4) * 8 + j;
    int n = nf * 16 + (lane & 15);
    float v = 0.f;
    if (k < K) v = (n < 64) ? Wl[k * 64 + n] : Wr[k * 64 + (n - 64)];
    unsigned int hb = bf16_rne(v);
    float hf = __uint_as_float(hb << 16);
    unsigned int lb = bf16_rne(v - hf);
    WF[(size_t)((kc * 8 + nf) * 2 + 0) * 512 + lane * 8 + j] = (short)hb;
    WF[(size_t)((kc * 8 + nf) * 2 + 1) * 512 + lane * 8 + j] = (short)lb;
}

// ---------------- MFMA GEMM, wave-independent, prefetched ----------------
// Each wave owns a 32x128 output tile (2 m-frags x 8 n-frags). A fragments read
// directly from global with one-chunk-ahead prefetch; W fragments from
// fragment-ordered global (L2/L1-resident) with one-nf-ahead prefetch.
// C restaged through per-wave padded LDS -> 1KB coalesced dwordx4 row stores.
template <int K, int LDX, int KC>
__global__ __launch_bounds__(256) void gemm_mfma(const float* __restrict__ X,
                                                 const short* __restrict__ WF,
                                                 float* __restrict__ O) {
    __shared__ float Cs[4][16 * 132];   // 8448 B per wave, 33.8 KB per block
    const int tid  = threadIdx.x;
    const int lane = tid & 63;
    const int wave = tid >> 6;
    const size_t rowbase = (size_t)(blockIdx.x * 4 + wave) * 32;
    const s16x8* WFv = (const s16x8*)WF;

    const int arow0 = (lane & 15);          // row within m-frag
    const int ak0   = (lane >> 4) * 8;      // k offset within 32-k chunk
    const f32x4 zero4 = (f32x4){0.f, 0.f, 0.f, 0.f};

    f32x4 acc[2][8];
#pragma unroll
    for (int m = 0; m < 2; m++)
#pragma unroll
        for (int nf = 0; nf < 8; nf++) acc[m][nf] = zero4;

    f32x4 av[2][2], pv[2][2];
#define LOADA(dst, kc_) {                                                     \
    _Pragma("unroll")                                                         \
    for (int m_ = 0; m_ < 2; m_++) {                                          \
        size_t row_ = rowbase + m_ * 16 + arow0;                              \
        int k0_ = (kc_) * 32 + ak0;                                           \
        dst[m_][0] = (k0_ + 4 <= K) ? *(const f32x4*)&X[row_ * (size_t)LDX + k0_] : zero4;     \
        dst[m_][1] = (k0_ + 8 <= K) ? *(const f32x4*)&X[row_ * (size_t)LDX + k0_ + 4] : zero4; \
    } }

    LOADA(av, 0);
    for (int kc = 0; kc < KC; kc++) {
        if (kc + 1 < KC) LOADA(pv, kc + 1);     // prefetch next A chunk
        s16x8 ah[2], al[2];
#pragma unroll
        for (int m = 0; m < 2; m++) split8(av[m][0], av[m][1], ah[m], al[m]);

        const s16x8* wb = WFv + (size_t)(kc * 8) * 128 + lane;
        s16x8 wh = wb[0], wl = wb[64];
#pragma unroll
        for (int nf = 0; nf < 8; nf++) {
            s16x8 wh2, wl2;
            if (nf < 7) { wh2 = wb[(nf + 1) * 128]; wl2 = wb[(nf + 1) * 128 + 64]; }
#pragma unroll
            for (int m = 0; m < 2; m++) {
                acc[m][nf] = __builtin_amdgcn_mfma_f32_16x16x32_bf16(ah[m], wh, acc[m][nf], 0, 0, 0);
                acc[m][nf] = __builtin_amdgcn_mfma_f32_16x16x32_bf16(al[m], wh, acc[m][nf], 0, 0, 0);
                acc[m][nf] = __builtin_amdgcn_mfma_f32_16x16x32_bf16(ah[m], wl, acc[m][nf], 0, 0, 0);
            }
            wh = wh2; wl = wl2;
        }
#pragma unroll
        for (int m = 0; m < 2; m++) {
            av[m][0] = pv[m][0];
            av[m][1] = pv[m][1];
        }
    }
#undef LOADA

    // ---- C restage: per-wave LDS (no barrier needed), coalesced stores ----
    float* cs = &Cs[wave][0];
#pragma unroll
    for (int m = 0; m < 2; m++) {
        const int srow = (lane >> 4) * 4;       // D frag: row (lane>>4)*4+r
        const int scol = lane & 15;             //          col nf*16+(lane&15)
#pragma unroll
        for (int nf = 0; nf < 8; nf++)
#pragma unroll
            for (int r = 0; r < 4; r++)
                cs[(srow + r) * 132 + nf * 16 + scol] = acc[m][nf][r];
        // read back row-major, 2 rows (1KB) per pass
#pragma unroll
        for (int p = 0; p < 8; p++) {
            int row = p * 2 + (lane >> 5);      // 0..15
            int col = (lane & 31) * 4;
            f32x4 v = *(const f32x4*)&cs[row * 132 + col];
            *(f32x4*)&O[(rowbase + m * 16 + row) * 128 + col] = v;
        }
    }
}

// ---------------- CSR build: one block per graph ----------------
__global__ __launch_bounds__(256) void csr_build(
    const int* __restrict__ esrc, const int* __restrict__ edst,
    int* __restrict__ csr_src, int* __restrict__ rowptr,
    int* __restrict__ degs, float* __restrict__ invdeg)
{
    __shared__ int cnt[NPG];
    __shared__ int off[NPG];
    __shared__ int cur[NPG];
    const int g = blockIdx.x, tid = threadIdx.x;
    const int ebase = g * EPG, nodebase = g * NPG;
    for (int i = tid; i < NPG; i += 256) cnt[i] = 0;
    __syncthreads();
    for (int e = tid; e < EPG; e += 256)
        atomicAdd(&cnt[edst[ebase + e] - nodebase], 1);
    __syncthreads();
    if (tid == 0) {
        int run = 0;
        for (int i = 0; i < NPG; i++) { off[i] = run; run += cnt[i]; }
    }
    __syncthreads();
    for (int i = tid; i < NPG; i += 256) {
        cur[i] = off[i];
        rowptr[nodebase + i] = off[i];
        degs[nodebase + i] = cnt[i];
        invdeg[nodebase + i] = 1.f / fmaxf((float)cnt[i], 1.f);
    }
    __syncthreads();
    for (int e = tid; e < EPG; e += 256) {
        int ld = edst[ebase + e] - nodebase;
        int p = atomicAdd(&cur[ld], 1);
        csr_src[ebase + p] = esrc[ebase + e] - nodebase;  // local src
    }
}

// ---------------- fused per-graph aggregate+combine (LDS-staged) ----------------
__global__ __launch_bounds__(1024) void agg_lds(
    const float* __restrict__ A,
    const int* __restrict__ csr_src, const int* __restrict__ rowptr,
    const int* __restrict__ degs, const float* __restrict__ invdeg,
    const float* __restrict__ bias,
    const float* __restrict__ resid,
    float* __restrict__ Xout)
{
    __shared__ float y[NPG * 64];     // 102400 B
    __shared__ int   csr_l[EPG];      // 25600 B
    const int g = blockIdx.x, tid = threadIdx.x;
    const int ebase = g * EPG, nodebase = g * NPG;

    for (int idx = tid; idx < NPG * 16; idx += 1024) {
        int node = idx >> 4, c4 = (idx & 15) * 4;
        *(float4*)&y[node * 64 + c4] =
            *(const float4*)&A[(size_t)(nodebase + node) * 128 + c4];
    }
    for (int e = tid; e < EPG; e += 1024) csr_l[e] = csr_src[ebase + e];
    __syncthreads();

    const int wave = tid >> 6, lane = tid & 63;
    for (int node = wave; node < NPG; node += 16) {
        const int start = rowptr[nodebase + node];
        const int dg = degs[nodebase + node];
        float acc = 0.f;
        int j = 0;
        for (; j + 4 <= dg; j += 4) {
            int s0 = csr_l[start + j];
            int s1 = csr_l[start + j + 1];
            int s2 = csr_l[start + j + 2];
            int s3 = csr_l[start + j + 3];
            acc += y[s0 * 64 + lane] + y[s1 * 64 + lane]
                 + y[s2 * 64 + lane] + y[s3 * 64 + lane];
        }
        for (; j < dg; j++) acc += y[csr_l[start + j] * 64 + lane];

        float v = acc * invdeg[nodebase + node] + bias[lane]
                + A[(size_t)(nodebase + node) * 128 + 64 + lane];
        v = fmaxf(v, 0.f);
        if (resid) v += resid[(size_t)(nodebase + node) * 64 + lane];
        Xout[(size_t)(nodebase + node) * 64 + lane] = v;
    }
}

// ---------------- per-graph score + top-k + pool + classifier ----------------
__global__ __launch_bounds__(256) void score_pool(
    const float* __restrict__ X3,
    const int* __restrict__ esrc, const int* __restrict__ edst,
    const float* __restrict__ Wpr, const float* __restrict__ bpr,
    const float* __restrict__ Wpo,
    const float* __restrict__ Wlin, const float* __restrict__ blin,
    float* __restrict__ out)
{
    __shared__ float t0[NPG], s[NPG], w[NPG];
    __shared__ float wpr[64], wpo[64];
    __shared__ float pp[4 * 64];
    __shared__ float pooled[64];
    __shared__ float lg[2];
    const int g = blockIdx.x, tid = threadIdx.x;
    if (tid < 64) { wpr[tid] = Wpr[tid]; wpo[tid] = Wpo[tid]; }
    __syncthreads();

    const int nodebase = g * NPG;
    for (int i = tid; i < NPG; i += 256) {
        const float* xr = &X3[(size_t)(nodebase + i) * 64];
        float a0 = 0.f, a1 = 0.f;
        for (int d = 0; d < 64; d++) { float x = xr[d]; a0 += x * wpr[d]; a1 += x * wpo[d]; }
        t0[i] = a0;
        s[i] = bpr[0] + a1;
    }
    __syncthreads();
    const int ebase = g * EPG;
    for (int e = tid; e < EPG; e += 256) {
        int ls = esrc[ebase + e] - nodebase;
        int ld = edst[ebase + e] - nodebase;
        atomicAdd(&s[ld], t0[ls]);
    }
    __syncthreads();
    for (int i = tid; i < NPG; i += 256) {
        float si = s[i];
        int cnt = 0;
        for (int j = 0; j < NPG; j++) {
            float sj = s[j];
            cnt += (sj > si) || (sj == si && j < i);
        }
        w[i] = (cnt < KSEL) ? tanhf(si) * (1.f / KSEL) : 0.f;
    }
    __syncthreads();
    const int d = tid & 63, part = tid >> 6;
    float acc = 0.f;
    for (int i = part * 100; i < part * 100 + 100; i++)
        acc += w[i] * X3[(size_t)(nodebase + i) * 64 + d];
    pp[part * 64 + d] = acc;
    __syncthreads();
    if (tid < 64) pooled[tid] = pp[tid] + pp[64 + tid] + pp[128 + tid] + pp[192 + tid];
    __syncthreads();
    if (tid < 2) {
        float l = blin[tid];
        for (int dd = 0; dd < 64; dd++) l += pooled[dd] * Wlin[dd * 2 + tid];
        lg[tid] = l;
    }
    __syncthreads();
    if (tid < 2) {
        float m = fmaxf(lg[0], lg[1]);
        float lse = m + logf(expf(lg[0] - m) + expf(lg[1] - m));
        out[g * 2 + tid] = lg[tid] - lse;
    }
}

extern "C" void kernel_launch(void* const* d_in, const int* in_sizes, int n_in,
                              void* d_out, int out_size, void* d_ws, size_t ws_size,
                              hipStream_t stream) {
    const float* x    = (const float*)d_in[0];
    const int*   eidx = (const int*)d_in[1];
    const float* W1l  = (const float*)d_in[3];
    const float* W1r  = (const float*)d_in[4];
    const float* b1   = (const float*)d_in[5];
    const float* W2l  = (const float*)d_in[6];
    const float* W2r  = (const float*)d_in[7];
    const float* b2   = (const float*)d_in[8];
    const float* W3l  = (const float*)d_in[9];
    const float* W3r  = (const float*)d_in[10];
    const float* b3   = (const float*)d_in[11];
    const float* Wpr  = (const float*)d_in[12];
    const float* bpr  = (const float*)d_in[13];
    const float* Wpo  = (const float*)d_in[14];
    const float* Wlin = (const float*)d_in[15];
    const float* blin = (const float*)d_in[16];

    const int N = in_sizes[0] / F_IN;       // 204800
    const int E = in_sizes[1] / 2;          // 3276800
    const int B = N / NPG;                  // 512
    const int* esrc = eidx;
    const int* edst = eidx + E;

    float* ws = (float*)d_ws;
    float* A      = ws;                                  // [N,128] yz buffer
    float* P0     = A + (size_t)N * 128;                 // [N,64] compact acts
    float* P1     = P0 + (size_t)N * 64;                 // [N,64] compact acts
    float* invdeg = P1 + (size_t)N * 64;                 // [N]
    short* WF1    = (short*)(invdeg + N);                // 7*8*2*512 shorts
    short* WF2    = WF1 + 57344;                         // 2*8*2*512 shorts
    short* WF3    = WF2 + 16384;
    int*   csr    = (int*)(WF3 + 16384);                 // [E] local src by dst
    int*   rowptr = csr + E;                             // [N] local offsets
    int*   degs   = rowptr + N;                          // [N]

    pack_wf<<<(7 * 4096 + 255) / 256, 256, 0, stream>>>(W1l, W1r, WF1, 200, 7);
    pack_wf<<<(2 * 4096 + 255) / 256, 256, 0, stream>>>(W2l, W2r, WF2, 64, 2);
    pack_wf<<<(2 * 4096 + 255) / 256, 256, 0, stream>>>(W3l, W3r, WF3, 64, 2);

    // CSR once (shared by all 3 layers)
    csr_build<<<B, 256, 0, stream>>>(esrc, edst, csr, rowptr, degs, invdeg);

    // layer 1: yz = x @ [W1l|W1r]; x1 -> P0
    gemm_mfma<200, 200, 7><<<N / 128, 256, 0, stream>>>(x, WF1, A);
    agg_lds<<<B, 1024, 0, stream>>>(A, csr, rowptr, degs, invdeg, b1, nullptr, P0);

    // layer 2: yz = x1 @ [W2l|W2r]; x2 = relu(...)+x1 -> P1
    gemm_mfma<64, 64, 2><<<N / 128, 256, 0, stream>>>(P0, WF2, A);
    agg_lds<<<B, 1024, 0, stream>>>(A, csr, rowptr, degs, invdeg, b2, P0, P1);

    // layer 3: yz = x2 @ [W3l|W3r]; x3 = relu(...)+x2 -> P0 (x1 dead)
    gemm_mfma<64, 64, 2><<<N / 128, 256, 0, stream>>>(P1, WF3, A);
    agg_lds<<<B, 1024, 0, stream>>>(A, csr, rowptr, degs, invdeg, b3, P1, P0);

    // score + top-k + pool + classifier
    score_pool<<<B, 256, 0, stream>>>(P0, esrc, edst, Wpr, bpr, Wpo, Wlin, blin,
                                      (float*)d_out);
}